// Round 10
// baseline (905.566 us; speedup 1.0000x reference)
//
#include <hip/hip_runtime.h>
#include <hip/hip_bf16.h>
#include <hip/hip_cooperative_groups.h>
#include <math.h>

namespace cg = cooperative_groups;

#define N_NODES 65536
#define NDIR 9
#define NEDGE 589824
#define TILE_M 32
#define CAP 512                     // per-block staged-edge capacity (Poisson(288)+13sigma)
#define APITCH 136

typedef __attribute__((ext_vector_type(8))) short short8;
typedef __attribute__((ext_vector_type(4))) float f32x4;

__device__ inline float bf2f(unsigned short u){ return __uint_as_float(((unsigned int)u)<<16); }
__device__ inline unsigned short f2bf(float f){
  unsigned int x = __float_as_uint(f);
  x += 0x7fff + ((x>>16)&1);           // round-to-nearest-even
  return (unsigned short)(x>>16);
}
__device__ inline float elu1(float x){ return x>0.f ? x : expm1f(x); }

__device__ inline void acc8(f32x4& a0, f32x4& a1, short8 v){
  a0[0] += bf2f((unsigned short)v[0]); a0[1] += bf2f((unsigned short)v[1]);
  a0[2] += bf2f((unsigned short)v[2]); a0[3] += bf2f((unsigned short)v[3]);
  a1[0] += bf2f((unsigned short)v[4]); a1[1] += bf2f((unsigned short)v[5]);
  a1[2] += bf2f((unsigned short)v[6]); a1[3] += bf2f((unsigned short)v[7]);
}

// ---- ONE cooperative kernel for the whole prep/CSR chain ----
// P0: zero hist | fold BN into W | biases | cast x->bf16      (independent, overlapped)
// P1: per-node histogram (atomics on 256KB hot array)
// P2: scan level-1 (blocks 0..63, 1024 ints each)
// P3: scan level-2 (block 0, 64 partial sums)
// P4: add offsets -> rs, cursor; sentinel
// P5: scatter packed keys (src | sel<<16) into per-node CSR
__global__ __launch_bounds__(256, 4) void chain_k(
    const float* __restrict__ x, unsigned short* __restrict__ xb,
    const float* __restrict__ W1, const float* __restrict__ W2,
    const float* __restrict__ W3,
    const float* __restrict__ b1, const float* __restrict__ g1,
    const float* __restrict__ be1, const float* __restrict__ rm1,
    const float* __restrict__ rv1,
    const float* __restrict__ b2, const float* __restrict__ g2,
    const float* __restrict__ be2, const float* __restrict__ rm2,
    const float* __restrict__ rv2,
    const float* __restrict__ b3, const float* __restrict__ g3,
    const float* __restrict__ be3, const float* __restrict__ rm3,
    const float* __restrict__ rv3,
    unsigned short* __restrict__ Wt1, unsigned short* __restrict__ Wt2,
    float* __restrict__ bias1, float* __restrict__ bias2,
    float* __restrict__ bias3, float* __restrict__ s3v,
    int* __restrict__ hist, int* __restrict__ rs, int* __restrict__ cursor,
    int* __restrict__ bsum, int* __restrict__ bsumx,
    const int* __restrict__ src, const int* __restrict__ dst,
    const int* __restrict__ sel, int* __restrict__ sorted){
  cg::grid_group grid = cg::this_grid();
  __shared__ int wsum[4];
  const float eps = 1e-5f;
  const int b = blockIdx.x, tid = threadIdx.x;
  const int gtid = b*256 + tid;
  const int gstride = gridDim.x*256;

  // ---- P0 ----
  for (int i = gtid; i < N_NODES/4; i += gstride){
    int4 z = {0,0,0,0};
    ((int4*)hist)[i] = z;
  }
  for (int idx = gtid; idx < (1280*128 + 1152*128); idx += gstride){
    if (idx < 1280*128) {
      int n = idx >> 7, k = idx & 127;
      float v;
      if (n < 1152) { int d = n >> 7, c = n & 127;
        float s = g1[c]*rsqrtf(rv1[c]+eps); v = W1[(d*128 + k)*128 + c] * s; }
      else { int c = n - 1152;
        float s = g3[c]*rsqrtf(rv3[c]+eps); v = W3[k*128 + c] * s; }
      Wt1[idx] = f2bf(v);
    } else {
      int j = idx - 1280*128;
      int n = j >> 7, k = j & 127;
      int d = n >> 7, c = n & 127;
      float s = g2[c]*rsqrtf(rv2[c]+eps);
      Wt2[j] = f2bf(W2[(d*128 + k)*128 + c] * s);
    }
  }
  if (gtid < 128){
    int c = gtid;
    float s1 = g1[c]*rsqrtf(rv1[c]+eps);
    bias1[c] = (b1[c]-rm1[c])*s1 + be1[c];
    float s2 = g2[c]*rsqrtf(rv2[c]+eps);
    bias2[c] = (b2[c]-rm2[c])*s2 + be2[c];
    float s3 = g3[c]*rsqrtf(rv3[c]+eps);
    bias3[c] = (b3[c]-rm3[c])*s3 + be3[c];
    s3v[c] = s3;
  }
  for (int i = gtid; i < N_NODES*128/8; i += gstride){
    f32x4 f0 = *(const f32x4*)(x + i*8);
    f32x4 f1 = *(const f32x4*)(x + i*8 + 4);
    short8 t;
    #pragma unroll
    for (int j = 0; j < 4; j++){ t[j] = (short)f2bf(f0[j]); t[4+j] = (short)f2bf(f1[j]); }
    *(short8*)(xb + i*8) = t;
  }
  grid.sync();

  // ---- P1: histogram ----
  for (int e = gtid; e < NEDGE; e += gstride)
    atomicAdd(&hist[dst[e]], 1);
  grid.sync();

  // ---- P2: scan level-1 (blocks 0..63 handle 1024 ints each) ----
  if (b < 64){
    int base = b*1024 + tid*4;
    int4 v = *(const int4*)(hist + base);
    int s = v.x + v.y + v.z + v.w;
    int lane = tid & 63, w = tid >> 6;
    int inc = s;
    #pragma unroll
    for (int o = 1; o < 64; o <<= 1){ int n = __shfl_up(inc, o); if (lane >= o) inc += n; }
    if (lane == 63) wsum[w] = inc;
    __syncthreads();
    int acc = 0;
    for (int i = 0; i < w; i++) acc += wsum[i];
    int ex = acc + inc - s;
    rs[base] = ex; rs[base+1] = ex + v.x; rs[base+2] = ex + v.x + v.y; rs[base+3] = ex + v.x + v.y + v.z;
    if (tid == 255) bsum[b] = acc + inc;
  }
  grid.sync();

  // ---- P3: scan level-2 (block 0, one wave over 64 sums) ----
  if (b == 0 && tid < 64){
    int v = bsum[tid];
    int inc = v;
    #pragma unroll
    for (int o = 1; o < 64; o <<= 1){ int n = __shfl_up(inc, o); if (tid >= o) inc += n; }
    bsumx[tid] = inc - v;                // exclusive
  }
  grid.sync();

  // ---- P4: global offsets ----
  for (int i = gtid; i < N_NODES; i += gstride){
    int v = rs[i] + bsumx[i >> 10];
    rs[i] = v; cursor[i] = v;
  }
  if (gtid == 0) rs[N_NODES] = NEDGE;    // sentinel
  grid.sync();

  // ---- P5: scatter packed keys ----
  for (int e = gtid; e < NEDGE; e += gstride){
    int pos = atomicAdd(&cursor[dst[e]], 1);
    sorted[pos] = src[e] | (sel[e] << 16);
  }
}

// ---- MFMA: wave computes all 32 rows x 32 cols (cols [w*32,w*32+32)) ----
__device__ __forceinline__ void mfma_tile(f32x4 acc[2][2],
                                          const unsigned short* agg,
                                          const unsigned short* __restrict__ Wd,
                                          int w, int q, int r){
  #pragma unroll
  for (int kk = 0; kk < 4; kk++){
    const unsigned short* wp = Wd + (size_t)(w*32 + r)*128 + kk*32 + q*8;
    short8 b0 = *(const short8*)wp;
    short8 b1 = *(const short8*)(wp + 16*128);
    #pragma unroll
    for (int mt = 0; mt < 2; mt++){
      short8 av = *(const short8*)&agg[(mt*16 + r)*APITCH + kk*32 + q*8];
      acc[mt][0] = __builtin_amdgcn_mfma_f32_16x16x32_bf16(av, b0, acc[mt][0], 0, 0, 0);
      acc[mt][1] = __builtin_amdgcn_mfma_f32_16x16x32_bf16(av, b1, acc[mt][1], 0, 0, 0);
    }
  }
}

// ---- fused layer (r9 measured-best, unchanged): v1 gather/MFMA core + in-LDS
// counting sort of packed (src,sel) edges into per-(row,dir) bins.
template<int IS_L2>
__global__ __launch_bounds__(256, 8) void layer_k(
    const unsigned short* __restrict__ H,     // layer input activations [N][128] bf16
    const unsigned short* __restrict__ X,     // xb (shortcut input, L2 only)
    const unsigned short* __restrict__ Wf,    // [1152][128] folded dir weights
    const unsigned short* __restrict__ W3f,   // [128][128] folded shortcut weights (L2)
    const int* __restrict__ rs, const int* __restrict__ sorted,
    const float* __restrict__ biasA, const float* __restrict__ bias3,
    const float* __restrict__ s3v,
    unsigned short* __restrict__ outB, float* __restrict__ outF){
  __shared__ __align__(16) unsigned short agg[TILE_M*APITCH];    // 8704 B
  __shared__ int skey[CAP];                                      // 2048 B packed keys
  __shared__ unsigned short skey2[CAP];                          // 1024 B sorted src
  __shared__ int rsl2[TILE_M + 1];                               // node offsets
  __shared__ int po[TILE_M*9];                                   // local bin starts
  __shared__ int wo[TILE_M*9];                                   // counts -> cursors -> ends
  const int tid = threadIdx.x;
  const int w = tid >> 6, lane = tid & 63;
  const int q = lane >> 4, r = lane & 15;
  const int rid = tid >> 4, c = tid & 15;                        // 16 lanes/row, chunk c
  const int m0 = blockIdx.x * TILE_M;

  if (tid <= TILE_M) rsl2[tid] = rs[m0 + tid];
  for (int i = tid; i < TILE_M*9; i += 256) wo[i] = 0;
  __syncthreads();
  const int lo = rsl2[0];
  const int cnt = rsl2[TILE_M] - lo;
  for (int i = tid; i < cnt && i < CAP; i += 256) skey[i] = sorted[lo + i];
  __syncthreads();

  // count per (node,dir): 8 threads per node walk its staged edges
  {
    const int nl8 = tid >> 3, sub = tid & 7;
    int s = rsl2[nl8] - lo, e = rsl2[nl8+1] - lo;
    if (e > CAP) e = CAP;
    for (int i = s + sub; i < e; i += 8)
      atomicAdd(&wo[nl8*9 + (skey[i] >> 16)], 1);
  }
  __syncthreads();
  // per-node prefix: po = bin start, wo = scatter cursor (becomes end after scatter)
  if (tid < TILE_M){
    int base = rsl2[tid] - lo;
    if (base > CAP) base = CAP;
    #pragma unroll
    for (int d = 0; d < 9; d++){
      int b = tid*9 + d;
      po[b] = base;
      int cc = wo[b];
      wo[b] = base;
      base += cc;
    }
  }
  __syncthreads();
  // scatter staged keys into per-(node,dir) bins (16-bit src)
  {
    const int nl8 = tid >> 3, sub = tid & 7;
    int s = rsl2[nl8] - lo, e = rsl2[nl8+1] - lo;
    if (e > CAP) e = CAP;
    for (int i = s + sub; i < e; i += 8){
      int k = skey[i];
      int pos = atomicAdd(&wo[nl8*9 + (k >> 16)], 1);
      skey2[pos] = (unsigned short)k;
    }
  }
  __syncthreads();

  f32x4 acc[2][2];
  #pragma unroll
  for (int mt = 0; mt < 2; mt++){ acc[mt][0] = (f32x4){0,0,0,0}; acc[mt][1] = (f32x4){0,0,0,0}; }

  #pragma unroll 1
  for (int d = 0; d < 9; d++){
    if (d) __syncthreads();              // agg consumed by previous mfma
    // stream A: row rid
    {
      int b = rid*9 + d;
      int s = po[b], e = wo[b];
      f32x4 a0 = {0,0,0,0}, a1 = {0,0,0,0};
      for (int i = s; i < e; i++){
        int key = skey2[i];
        short8 v = *(const short8*)(H + (size_t)key*128 + c*8);
        acc8(a0, a1, v);
      }
      // tail fallback (only if this node's edges overflowed CAP)
      int ts = rsl2[rid] - lo; if (ts < CAP) ts = CAP;
      int te = rsl2[rid+1] - lo;
      for (int i = ts; i < te; i++){
        int k = sorted[lo + i];
        if ((k >> 16) == d){
          short8 v = *(const short8*)(H + (size_t)(k & 0xFFFF)*128 + c*8);
          acc8(a0, a1, v);
        }
      }
      short8 o;
      o[0]=(short)f2bf(a0[0]); o[1]=(short)f2bf(a0[1]); o[2]=(short)f2bf(a0[2]); o[3]=(short)f2bf(a0[3]);
      o[4]=(short)f2bf(a1[0]); o[5]=(short)f2bf(a1[1]); o[6]=(short)f2bf(a1[2]); o[7]=(short)f2bf(a1[3]);
      *(short8*)&agg[rid*APITCH + c*8] = o;
    }
    // stream B: row rid+16
    {
      int b = (16 + rid)*9 + d;
      int s = po[b], e = wo[b];
      f32x4 a0 = {0,0,0,0}, a1 = {0,0,0,0};
      for (int i = s; i < e; i++){
        int key = skey2[i];
        short8 v = *(const short8*)(H + (size_t)key*128 + c*8);
        acc8(a0, a1, v);
      }
      int ts = rsl2[16+rid] - lo; if (ts < CAP) ts = CAP;
      int te = rsl2[16+rid+1] - lo;
      for (int i = ts; i < te; i++){
        int k = sorted[lo + i];
        if ((k >> 16) == d){
          short8 v = *(const short8*)(H + (size_t)(k & 0xFFFF)*128 + c*8);
          acc8(a0, a1, v);
        }
      }
      short8 o;
      o[0]=(short)f2bf(a0[0]); o[1]=(short)f2bf(a0[1]); o[2]=(short)f2bf(a0[2]); o[3]=(short)f2bf(a0[3]);
      o[4]=(short)f2bf(a1[0]); o[5]=(short)f2bf(a1[1]); o[6]=(short)f2bf(a1[2]); o[7]=(short)f2bf(a1[3]);
      *(short8*)&agg[(16 + rid)*APITCH + c*8] = o;
    }
    __syncthreads();
    mfma_tile(acc, agg, Wf + (size_t)d*128*128, w, q, r);
  }

  if constexpr (!IS_L2){
    #pragma unroll
    for (int mt = 0; mt < 2; mt++)
      #pragma unroll
      for (int n2 = 0; n2 < 2; n2++){
        int col = w*32 + n2*16 + r;
        float bA = biasA[col];
        #pragma unroll
        for (int rr = 0; rr < 4; rr++){
          int row = m0 + mt*16 + q*4 + rr;
          outB[(size_t)row*128 + col] = f2bf(elu1(acc[mt][n2][rr] + bA));
        }
      }
  } else {
    // 10th phase: shortcut over dir-0 bins from X, MFMA with W3f
    __syncthreads();                     // agg consumed by last mfma
    #pragma unroll
    for (int t2 = 0; t2 < 2; t2++){
      int nl = t2*16 + rid;
      int b = nl*9;
      int s = po[b], e = wo[b];
      f32x4 a0 = {0,0,0,0}, a1 = {0,0,0,0};
      for (int i = s; i < e; i++){
        int key = skey2[i];
        short8 v = *(const short8*)(X + (size_t)key*128 + c*8);
        acc8(a0, a1, v);
      }
      int ts = rsl2[nl] - lo; if (ts < CAP) ts = CAP;
      int te = rsl2[nl+1] - lo;
      for (int i = ts; i < te; i++){
        int k = sorted[lo + i];
        if ((k >> 16) == 0){
          short8 v = *(const short8*)(X + (size_t)(k & 0xFFFF)*128 + c*8);
          acc8(a0, a1, v);
        }
      }
      short8 o;
      o[0]=(short)f2bf(a0[0]); o[1]=(short)f2bf(a0[1]); o[2]=(short)f2bf(a0[2]); o[3]=(short)f2bf(a0[3]);
      o[4]=(short)f2bf(a1[0]); o[5]=(short)f2bf(a1[1]); o[6]=(short)f2bf(a1[2]); o[7]=(short)f2bf(a1[3]);
      *(short8*)&agg[nl*APITCH + c*8] = o;
    }
    __syncthreads();
    f32x4 sca[2][2];
    #pragma unroll
    for (int mt = 0; mt < 2; mt++){ sca[mt][0] = (f32x4){0,0,0,0}; sca[mt][1] = (f32x4){0,0,0,0}; }
    mfma_tile(sca, agg, W3f, w, q, r);
    #pragma unroll
    for (int mt = 0; mt < 2; mt++)
      #pragma unroll
      for (int n2 = 0; n2 < 2; n2++){
        int col = w*32 + n2*16 + r;
        float bA = biasA[col], b3 = bias3[col], s3 = s3v[col];
        #pragma unroll
        for (int rr = 0; rr < 4; rr++){
          int row = m0 + mt*16 + q*4 + rr;
          float h = elu1(acc[mt][n2][rr] + bA);
          outF[(size_t)row*128 + col] = elu1(h*s3 + sca[mt][n2][rr] + b3);
        }
      }
  }
}

extern "C" void kernel_launch(void* const* d_in, const int* in_sizes, int n_in,
                              void* d_out, int out_size, void* d_ws, size_t ws_size,
                              hipStream_t stream){
  const float* x   = (const float*)d_in[0];
  const int*   ei  = (const int*)d_in[1];
  const int*   sel = (const int*)d_in[2];
  const float* W1  = (const float*)d_in[3];
  const float* b1  = (const float*)d_in[4];
  const float* g1  = (const float*)d_in[5];
  const float* be1 = (const float*)d_in[6];
  const float* rm1 = (const float*)d_in[7];
  const float* rv1 = (const float*)d_in[8];
  const float* W2  = (const float*)d_in[9];
  const float* b2  = (const float*)d_in[10];
  const float* g2  = (const float*)d_in[11];
  const float* be2 = (const float*)d_in[12];
  const float* rm2 = (const float*)d_in[13];
  const float* rv2 = (const float*)d_in[14];
  const float* W3  = (const float*)d_in[15];
  const float* b3  = (const float*)d_in[16];
  const float* g3  = (const float*)d_in[17];
  const float* be3 = (const float*)d_in[18];
  const float* rm3 = (const float*)d_in[19];
  const float* rv3 = (const float*)d_in[20];

  char* ws = (char*)d_ws;
  unsigned short* xb   = (unsigned short*)(ws);                  // 16.78 MB
  unsigned short* h1   = (unsigned short*)(ws + 16777216);       // 16.78 MB
  unsigned short* Wt1  = (unsigned short*)(ws + 33554432);       // 327,680 B
  unsigned short* Wt2  = (unsigned short*)(ws + 33882112);       // 294,912 B
  float* bias1  = (float*)(ws + 34177024);
  float* bias2  = bias1 + 128;
  float* bias3  = bias1 + 256;
  float* s3v    = bias1 + 384;
  int* hist     = (int*)(ws + 34179072);                         // 256 KB used
  int* rs       = (int*)(ws + 36538368);                         // 64K+1 ints used
  int* cursor   = (int*)(ws + 38897920);                         // 256 KB used
  int* bsum     = (int*)(ws + 41257216);                         // 4 KB
  int* bsumx    = (int*)(ws + 41261312);                         // 4 KB
  int* sorted   = (int*)(ws + 41265664);                         // 2.36 MB packed keys

  const int* srcp = ei;
  const int* dstp = ei + NEDGE;

  void* args[] = {
    (void*)&x, (void*)&xb, (void*)&W1, (void*)&W2, (void*)&W3,
    (void*)&b1, (void*)&g1, (void*)&be1, (void*)&rm1, (void*)&rv1,
    (void*)&b2, (void*)&g2, (void*)&be2, (void*)&rm2, (void*)&rv2,
    (void*)&b3, (void*)&g3, (void*)&be3, (void*)&rm3, (void*)&rv3,
    (void*)&Wt1, (void*)&Wt2, (void*)&bias1, (void*)&bias2,
    (void*)&bias3, (void*)&s3v,
    (void*)&hist, (void*)&rs, (void*)&cursor, (void*)&bsum, (void*)&bsumx,
    (void*)&srcp, (void*)&dstp, (void*)&sel, (void*)&sorted
  };
  hipLaunchCooperativeKernel((const void*)chain_k, dim3(1024), dim3(256),
                             args, 0, stream);

  layer_k<0><<<2048, 256, 0, stream>>>(xb, nullptr, Wt1, nullptr, rs, sorted,
                                       bias1, nullptr, nullptr, h1, nullptr);
  layer_k<1><<<2048, 256, 0, stream>>>(h1, xb, Wt2, Wt1 + 1152*128, rs, sorted,
                                       bias2, bias3, s3v, nullptr, (float*)d_out);
}

// Round 11
// 332.506 us; speedup vs baseline: 2.7235x; 2.7235x over previous
//
#include <hip/hip_runtime.h>
#include <hip/hip_bf16.h>
#include <math.h>

#define N_NODES 65536
#define NDIR 9
#define NEDGE 589824
#define TILE_M 32
#define SLOTS 24                    // fixed slots per node (Poisson(9); P(deg>24)~8e-6)
#define OCAP 65536                  // overflow list capacity (entries)
#define APITCH 136

typedef __attribute__((ext_vector_type(8))) short short8;
typedef __attribute__((ext_vector_type(4))) float f32x4;

__device__ inline float bf2f(unsigned short u){ return __uint_as_float(((unsigned int)u)<<16); }
__device__ inline unsigned short f2bf(float f){
  unsigned int x = __float_as_uint(f);
  x += 0x7fff + ((x>>16)&1);           // round-to-nearest-even
  return (unsigned short)(x>>16);
}
__device__ inline float elu1(float x){ return x>0.f ? x : expm1f(x); }

__device__ inline void acc8(f32x4& a0, f32x4& a1, short8 v){
  a0[0] += bf2f((unsigned short)v[0]); a0[1] += bf2f((unsigned short)v[1]);
  a0[2] += bf2f((unsigned short)v[2]); a0[3] += bf2f((unsigned short)v[3]);
  a1[0] += bf2f((unsigned short)v[4]); a1[1] += bf2f((unsigned short)v[5]);
  a1[2] += bf2f((unsigned short)v[6]); a1[3] += bf2f((unsigned short)v[7]);
}

// ---- fused prep: zero cnt | fold BN into W (bf16, transposed) | biases | cast x ----
// blocks [0,64): zero cnt (64K ints). [64,1280): prep_w. 1280: biases + ocnt=0.
// [1281,5377): xcast.
__global__ void prep_all(const float* __restrict__ x, unsigned short* __restrict__ xb,
                         const float* __restrict__ W1, const float* __restrict__ W2,
                         const float* __restrict__ W3,
                         const float* __restrict__ b1, const float* __restrict__ g1,
                         const float* __restrict__ be1, const float* __restrict__ rm1,
                         const float* __restrict__ rv1,
                         const float* __restrict__ b2, const float* __restrict__ g2,
                         const float* __restrict__ be2, const float* __restrict__ rm2,
                         const float* __restrict__ rv2,
                         const float* __restrict__ b3, const float* __restrict__ g3,
                         const float* __restrict__ be3, const float* __restrict__ rm3,
                         const float* __restrict__ rv3,
                         unsigned short* __restrict__ Wt1, unsigned short* __restrict__ Wt2,
                         float* __restrict__ bias1, float* __restrict__ bias2,
                         float* __restrict__ bias3, float* __restrict__ s3v,
                         int* __restrict__ cnt, int* __restrict__ ocnt){
  const float eps = 1e-5f;
  int b = blockIdx.x, tid = threadIdx.x;
  if (b < 64){
    int4 z = {0,0,0,0};
    *(int4*)&cnt[(b*256 + tid)*4] = z;
  } else if (b < 1280){
    int idx = (b - 64)*256 + tid;
    if (idx < 1280*128) {
      int n = idx >> 7, k = idx & 127;
      float v;
      if (n < 1152) { int d = n >> 7, c = n & 127;
        float s = g1[c]*rsqrtf(rv1[c]+eps); v = W1[(d*128 + k)*128 + c] * s; }
      else { int c = n - 1152;
        float s = g3[c]*rsqrtf(rv3[c]+eps); v = W3[k*128 + c] * s; }
      Wt1[idx] = f2bf(v);
    } else {
      int j = idx - 1280*128;
      int n = j >> 7, k = j & 127;
      int d = n >> 7, c = n & 127;
      float s = g2[c]*rsqrtf(rv2[c]+eps);
      Wt2[j] = f2bf(W2[(d*128 + k)*128 + c] * s);
    }
  } else if (b == 1280){
    if (tid < 128){
      int c = tid;
      float s1 = g1[c]*rsqrtf(rv1[c]+eps);
      bias1[c] = (b1[c]-rm1[c])*s1 + be1[c];
      float s2 = g2[c]*rsqrtf(rv2[c]+eps);
      bias2[c] = (b2[c]-rm2[c])*s2 + be2[c];
      float s3 = g3[c]*rsqrtf(rv3[c]+eps);
      bias3[c] = (b3[c]-rm3[c])*s3 + be3[c];
      s3v[c] = s3;
    } else if (tid == 128){
      *ocnt = 0;
    }
  } else {
    int i = ((b - 1281)*256 + tid)*8;
    f32x4 f0 = *(const f32x4*)(x + i);
    f32x4 f1 = *(const f32x4*)(x + i + 4);
    short8 t;
    #pragma unroll
    for (int j = 0; j < 4; j++){ t[j] = (short)f2bf(f0[j]); t[4+j] = (short)f2bf(f1[j]); }
    *(short8*)(xb + i) = t;
  }
}

// ---- direct fixed-slot scatter: sorted[dst][slot] = src | sel<<16; no hist/scan ----
__global__ void scatter_k(const int* __restrict__ src, const int* __restrict__ dst,
                          const int* __restrict__ sel,
                          int* __restrict__ cnt, int* __restrict__ sorted,
                          int* __restrict__ ocnt, int* __restrict__ overflow){
  int e = blockIdx.x*256 + threadIdx.x;
  int d = dst[e];
  int key = src[e] | (sel[e] << 16);
  int pos = atomicAdd(&cnt[d], 1);
  if (pos < SLOTS){
    sorted[d*SLOTS + pos] = key;
  } else {
    int oi = atomicAdd(ocnt, 1);
    if (oi < OCAP){ overflow[oi*2] = d; overflow[oi*2 + 1] = key; }
  }
}

// ---- MFMA: wave computes all 32 rows x 32 cols (cols [w*32,w*32+32)) ----
__device__ __forceinline__ void mfma_tile(f32x4 acc[2][2],
                                          const unsigned short* agg,
                                          const unsigned short* __restrict__ Wd,
                                          int w, int q, int r){
  #pragma unroll
  for (int kk = 0; kk < 4; kk++){
    const unsigned short* wp = Wd + (size_t)(w*32 + r)*128 + kk*32 + q*8;
    short8 b0 = *(const short8*)wp;
    short8 b1 = *(const short8*)(wp + 16*128);
    #pragma unroll
    for (int mt = 0; mt < 2; mt++){
      short8 av = *(const short8*)&agg[(mt*16 + r)*APITCH + kk*32 + q*8];
      acc[mt][0] = __builtin_amdgcn_mfma_f32_16x16x32_bf16(av, b0, acc[mt][0], 0, 0, 0);
      acc[mt][1] = __builtin_amdgcn_mfma_f32_16x16x32_bf16(av, b1, acc[mt][1], 0, 0, 0);
    }
  }
}

// ---- fused layer (r9 measured-best core): v1 gather/MFMA + in-LDS counting sort,
// fed from the fixed-slot CSR (cnt + sorted[node][SLOTS]); overflow list handled
// in-loop (empty in practice).
template<int IS_L2>
__global__ __launch_bounds__(256, 8) void layer_k(
    const unsigned short* __restrict__ H,     // layer input activations [N][128] bf16
    const unsigned short* __restrict__ X,     // xb (shortcut input, L2 only)
    const unsigned short* __restrict__ Wf,    // [1152][128] folded dir weights
    const unsigned short* __restrict__ W3f,   // [128][128] folded shortcut weights (L2)
    const int* __restrict__ cntg, const int* __restrict__ sorted,
    const int* __restrict__ ocnt, const int* __restrict__ overflow,
    const float* __restrict__ biasA, const float* __restrict__ bias3,
    const float* __restrict__ s3v,
    unsigned short* __restrict__ outB, float* __restrict__ outF){
  __shared__ __align__(16) unsigned short agg[TILE_M*APITCH];    // 8704 B
  __shared__ int skey[TILE_M*SLOTS];                             // 3072 B staged keys
  __shared__ unsigned short skey2[TILE_M*SLOTS];                 // 1536 B sorted src
  __shared__ int cnts[TILE_M];                                   // per-node counts
  __shared__ int po[TILE_M*9];                                   // local bin starts
  __shared__ int wo[TILE_M*9];                                   // counts -> cursors -> ends
  __shared__ int ocs;
  const int tid = threadIdx.x;
  const int w = tid >> 6, lane = tid & 63;
  const int q = lane >> 4, r = lane & 15;
  const int rid = tid >> 4, c = tid & 15;                        // 16 lanes/row, chunk c
  const int m0 = blockIdx.x * TILE_M;

  if (tid < TILE_M){ int v = cntg[m0 + tid]; cnts[tid] = v < SLOTS ? v : SLOTS; }
  if (tid == 255){ int v = *ocnt; ocs = v < OCAP ? v : OCAP; }
  for (int i = tid; i < TILE_M*9; i += 256) wo[i] = 0;
  __syncthreads();

  // stage fixed-slot keys + count per (node,dir): 8 threads per node
  {
    const int nl8 = tid >> 3, sub = tid & 7;
    int e8 = cnts[nl8];
    for (int j = sub; j < e8; j += 8){
      int k = sorted[(m0 + nl8)*SLOTS + j];
      skey[nl8*SLOTS + j] = k;
      atomicAdd(&wo[nl8*9 + (k >> 16)], 1);
    }
  }
  __syncthreads();
  // per-node prefix: po = bin start, wo = scatter cursor (becomes end after scatter)
  if (tid < TILE_M){
    int base = tid*SLOTS;
    #pragma unroll
    for (int d = 0; d < 9; d++){
      int b = tid*9 + d;
      po[b] = base;
      int cc = wo[b];
      wo[b] = base;
      base += cc;
    }
  }
  __syncthreads();
  // scatter staged keys into per-(node,dir) bins (16-bit src)
  {
    const int nl8 = tid >> 3, sub = tid & 7;
    int e8 = cnts[nl8];
    for (int j = sub; j < e8; j += 8){
      int k = skey[nl8*SLOTS + j];
      int pos = atomicAdd(&wo[nl8*9 + (k >> 16)], 1);
      skey2[pos] = (unsigned short)k;
    }
  }
  __syncthreads();

  f32x4 acc[2][2];
  #pragma unroll
  for (int mt = 0; mt < 2; mt++){ acc[mt][0] = (f32x4){0,0,0,0}; acc[mt][1] = (f32x4){0,0,0,0}; }

  #pragma unroll 1
  for (int d = 0; d < 9; d++){
    if (d) __syncthreads();              // agg consumed by previous mfma
    // stream A: row rid
    {
      int b = rid*9 + d;
      int s = po[b], e = wo[b];
      f32x4 a0 = {0,0,0,0}, a1 = {0,0,0,0};
      for (int i = s; i < e; i++){
        int key = skey2[i];
        short8 v = *(const short8*)(H + (size_t)key*128 + c*8);
        acc8(a0, a1, v);
      }
      for (int i = 0; i < ocs; i++){     // overflow (empty in practice)
        if (overflow[i*2] == m0 + rid && (overflow[i*2+1] >> 16) == d){
          short8 v = *(const short8*)(H + (size_t)(overflow[i*2+1] & 0xFFFF)*128 + c*8);
          acc8(a0, a1, v);
        }
      }
      short8 o;
      o[0]=(short)f2bf(a0[0]); o[1]=(short)f2bf(a0[1]); o[2]=(short)f2bf(a0[2]); o[3]=(short)f2bf(a0[3]);
      o[4]=(short)f2bf(a1[0]); o[5]=(short)f2bf(a1[1]); o[6]=(short)f2bf(a1[2]); o[7]=(short)f2bf(a1[3]);
      *(short8*)&agg[rid*APITCH + c*8] = o;
    }
    // stream B: row rid+16
    {
      int b = (16 + rid)*9 + d;
      int s = po[b], e = wo[b];
      f32x4 a0 = {0,0,0,0}, a1 = {0,0,0,0};
      for (int i = s; i < e; i++){
        int key = skey2[i];
        short8 v = *(const short8*)(H + (size_t)key*128 + c*8);
        acc8(a0, a1, v);
      }
      for (int i = 0; i < ocs; i++){
        if (overflow[i*2] == m0 + 16 + rid && (overflow[i*2+1] >> 16) == d){
          short8 v = *(const short8*)(H + (size_t)(overflow[i*2+1] & 0xFFFF)*128 + c*8);
          acc8(a0, a1, v);
        }
      }
      short8 o;
      o[0]=(short)f2bf(a0[0]); o[1]=(short)f2bf(a0[1]); o[2]=(short)f2bf(a0[2]); o[3]=(short)f2bf(a0[3]);
      o[4]=(short)f2bf(a1[0]); o[5]=(short)f2bf(a1[1]); o[6]=(short)f2bf(a1[2]); o[7]=(short)f2bf(a1[3]);
      *(short8*)&agg[(16 + rid)*APITCH + c*8] = o;
    }
    __syncthreads();
    mfma_tile(acc, agg, Wf + (size_t)d*128*128, w, q, r);
  }

  if constexpr (!IS_L2){
    #pragma unroll
    for (int mt = 0; mt < 2; mt++)
      #pragma unroll
      for (int n2 = 0; n2 < 2; n2++){
        int col = w*32 + n2*16 + r;
        float bA = biasA[col];
        #pragma unroll
        for (int rr = 0; rr < 4; rr++){
          int row = m0 + mt*16 + q*4 + rr;
          outB[(size_t)row*128 + col] = f2bf(elu1(acc[mt][n2][rr] + bA));
        }
      }
  } else {
    // 10th phase: shortcut over dir-0 bins from X, MFMA with W3f
    __syncthreads();                     // agg consumed by last mfma
    #pragma unroll
    for (int t2 = 0; t2 < 2; t2++){
      int nl = t2*16 + rid;
      int b = nl*9;
      int s = po[b], e = wo[b];
      f32x4 a0 = {0,0,0,0}, a1 = {0,0,0,0};
      for (int i = s; i < e; i++){
        int key = skey2[i];
        short8 v = *(const short8*)(X + (size_t)key*128 + c*8);
        acc8(a0, a1, v);
      }
      for (int i = 0; i < ocs; i++){
        if (overflow[i*2] == m0 + nl && (overflow[i*2+1] >> 16) == 0){
          short8 v = *(const short8*)(X + (size_t)(overflow[i*2+1] & 0xFFFF)*128 + c*8);
          acc8(a0, a1, v);
        }
      }
      short8 o;
      o[0]=(short)f2bf(a0[0]); o[1]=(short)f2bf(a0[1]); o[2]=(short)f2bf(a0[2]); o[3]=(short)f2bf(a0[3]);
      o[4]=(short)f2bf(a1[0]); o[5]=(short)f2bf(a1[1]); o[6]=(short)f2bf(a1[2]); o[7]=(short)f2bf(a1[3]);
      *(short8*)&agg[nl*APITCH + c*8] = o;
    }
    __syncthreads();
    f32x4 sca[2][2];
    #pragma unroll
    for (int mt = 0; mt < 2; mt++){ sca[mt][0] = (f32x4){0,0,0,0}; sca[mt][1] = (f32x4){0,0,0,0}; }
    mfma_tile(sca, agg, W3f, w, q, r);
    #pragma unroll
    for (int mt = 0; mt < 2; mt++)
      #pragma unroll
      for (int n2 = 0; n2 < 2; n2++){
        int col = w*32 + n2*16 + r;
        float bA = biasA[col], b3 = bias3[col], s3 = s3v[col];
        #pragma unroll
        for (int rr = 0; rr < 4; rr++){
          int row = m0 + mt*16 + q*4 + rr;
          float h = elu1(acc[mt][n2][rr] + bA);
          outF[(size_t)row*128 + col] = elu1(h*s3 + sca[mt][n2][rr] + b3);
        }
      }
  }
}

extern "C" void kernel_launch(void* const* d_in, const int* in_sizes, int n_in,
                              void* d_out, int out_size, void* d_ws, size_t ws_size,
                              hipStream_t stream){
  const float* x   = (const float*)d_in[0];
  const int*   ei  = (const int*)d_in[1];
  const int*   sel = (const int*)d_in[2];
  const float* W1  = (const float*)d_in[3];
  const float* b1  = (const float*)d_in[4];
  const float* g1  = (const float*)d_in[5];
  const float* be1 = (const float*)d_in[6];
  const float* rm1 = (const float*)d_in[7];
  const float* rv1 = (const float*)d_in[8];
  const float* W2  = (const float*)d_in[9];
  const float* b2  = (const float*)d_in[10];
  const float* g2  = (const float*)d_in[11];
  const float* be2 = (const float*)d_in[12];
  const float* rm2 = (const float*)d_in[13];
  const float* rv2 = (const float*)d_in[14];
  const float* W3  = (const float*)d_in[15];
  const float* b3  = (const float*)d_in[16];
  const float* g3  = (const float*)d_in[17];
  const float* be3 = (const float*)d_in[18];
  const float* rm3 = (const float*)d_in[19];
  const float* rv3 = (const float*)d_in[20];

  char* ws = (char*)d_ws;
  unsigned short* xb   = (unsigned short*)(ws);                  // 16,777,216 B
  unsigned short* h1   = (unsigned short*)(ws + 16777216);       // 16,777,216 B
  unsigned short* Wt1  = (unsigned short*)(ws + 33554432);       // 327,680 B
  unsigned short* Wt2  = (unsigned short*)(ws + 33882112);       // 294,912 B
  float* bias1  = (float*)(ws + 34177024);
  float* bias2  = bias1 + 128;
  float* bias3  = bias1 + 256;
  float* s3v    = bias1 + 384;
  int* cnt      = (int*)(ws + 34179072);                         // 262,144 B
  int* ocnt     = (int*)(ws + 34441216);                         // 256 B (pad)
  int* overflow = (int*)(ws + 34441472);                         // 524,288 B
  int* sorted   = (int*)(ws + 34965760);                         // 6,291,456 B -> ends 41,257,216

  const int* srcp = ei;
  const int* dstp = ei + NEDGE;

  prep_all<<<5377, 256, 0, stream>>>(x, xb, W1, W2, W3,
                                     b1, g1, be1, rm1, rv1,
                                     b2, g2, be2, rm2, rv2,
                                     b3, g3, be3, rm3, rv3,
                                     Wt1, Wt2, bias1, bias2, bias3, s3v,
                                     cnt, ocnt);
  scatter_k<<<NEDGE/256, 256, 0, stream>>>(srcp, dstp, sel, cnt, sorted, ocnt, overflow);

  layer_k<0><<<2048, 256, 0, stream>>>(xb, nullptr, Wt1, nullptr, cnt, sorted,
                                       ocnt, overflow,
                                       bias1, nullptr, nullptr, h1, nullptr);
  layer_k<1><<<2048, 256, 0, stream>>>(h1, xb, Wt2, Wt1 + 1152*128, cnt, sorted,
                                       ocnt, overflow,
                                       bias2, bias3, s3v, nullptr, (float*)d_out);
}

// Round 12
// 332.298 us; speedup vs baseline: 2.7252x; 1.0006x over previous
//
#include <hip/hip_runtime.h>
#include <hip/hip_bf16.h>
#include <math.h>

#define N_NODES 65536
#define NDIR 9
#define NEDGE 589824
#define TILE_M 32
#define SLOTS 24                    // fixed slots per node (Poisson(9); P(deg>24)~8e-6)
#define OCAP 65536                  // overflow list capacity (entries)
#define APITCH 136

typedef __attribute__((ext_vector_type(8))) short short8;
typedef __attribute__((ext_vector_type(4))) float f32x4;

__device__ inline float bf2f(unsigned short u){ return __uint_as_float(((unsigned int)u)<<16); }
__device__ inline unsigned short f2bf(float f){
  unsigned int x = __float_as_uint(f);
  x += 0x7fff + ((x>>16)&1);           // round-to-nearest-even
  return (unsigned short)(x>>16);
}
__device__ inline float elu1(float x){ return x>0.f ? x : expm1f(x); }

__device__ inline void acc8(f32x4& a0, f32x4& a1, short8 v){
  a0[0] += bf2f((unsigned short)v[0]); a0[1] += bf2f((unsigned short)v[1]);
  a0[2] += bf2f((unsigned short)v[2]); a0[3] += bf2f((unsigned short)v[3]);
  a1[0] += bf2f((unsigned short)v[4]); a1[1] += bf2f((unsigned short)v[5]);
  a1[2] += bf2f((unsigned short)v[6]); a1[3] += bf2f((unsigned short)v[7]);
}

// ---- ONE fused prep+scatter kernel (cnt/ocnt pre-zeroed by hipMemsetAsync) ----
// blocks [0,2304): scatter (latency-bound, starts first).
// [2304,3520): prep_w. 3520: biases. [3521,7617): xcast (BW-bound filler).
__global__ void fuse_k(const float* __restrict__ x, unsigned short* __restrict__ xb,
                       const float* __restrict__ W1, const float* __restrict__ W2,
                       const float* __restrict__ W3,
                       const float* __restrict__ b1, const float* __restrict__ g1,
                       const float* __restrict__ be1, const float* __restrict__ rm1,
                       const float* __restrict__ rv1,
                       const float* __restrict__ b2, const float* __restrict__ g2,
                       const float* __restrict__ be2, const float* __restrict__ rm2,
                       const float* __restrict__ rv2,
                       const float* __restrict__ b3, const float* __restrict__ g3,
                       const float* __restrict__ be3, const float* __restrict__ rm3,
                       const float* __restrict__ rv3,
                       unsigned short* __restrict__ Wt1, unsigned short* __restrict__ Wt2,
                       float* __restrict__ bias1, float* __restrict__ bias2,
                       float* __restrict__ bias3, float* __restrict__ s3v,
                       int* __restrict__ cnt, int* __restrict__ ocnt,
                       int* __restrict__ overflow,
                       const int* __restrict__ src, const int* __restrict__ dst,
                       const int* __restrict__ sel, int* __restrict__ sorted){
  const float eps = 1e-5f;
  int b = blockIdx.x, tid = threadIdx.x;
  if (b < 2304){
    int e = b*256 + tid;
    int d = dst[e];
    int key = src[e] | (sel[e] << 16);
    int pos = atomicAdd(&cnt[d], 1);
    if (pos < SLOTS){
      sorted[d*SLOTS + pos] = key;
    } else {
      int oi = atomicAdd(ocnt, 1);
      if (oi < OCAP){ overflow[oi*2] = d; overflow[oi*2 + 1] = key; }
    }
  } else if (b < 3520){
    int idx = (b - 2304)*256 + tid;
    if (idx < 1280*128) {
      int n = idx >> 7, k = idx & 127;
      float v;
      if (n < 1152) { int d = n >> 7, c = n & 127;
        float s = g1[c]*rsqrtf(rv1[c]+eps); v = W1[(d*128 + k)*128 + c] * s; }
      else { int c = n - 1152;
        float s = g3[c]*rsqrtf(rv3[c]+eps); v = W3[k*128 + c] * s; }
      Wt1[idx] = f2bf(v);
    } else {
      int j = idx - 1280*128;
      int n = j >> 7, k = j & 127;
      int d = n >> 7, c = n & 127;
      float s = g2[c]*rsqrtf(rv2[c]+eps);
      Wt2[j] = f2bf(W2[(d*128 + k)*128 + c] * s);
    }
  } else if (b == 3520){
    if (tid < 128){
      int c = tid;
      float s1 = g1[c]*rsqrtf(rv1[c]+eps);
      bias1[c] = (b1[c]-rm1[c])*s1 + be1[c];
      float s2 = g2[c]*rsqrtf(rv2[c]+eps);
      bias2[c] = (b2[c]-rm2[c])*s2 + be2[c];
      float s3 = g3[c]*rsqrtf(rv3[c]+eps);
      bias3[c] = (b3[c]-rm3[c])*s3 + be3[c];
      s3v[c] = s3;
    }
  } else {
    int i = ((b - 3521)*256 + tid)*8;
    f32x4 f0 = *(const f32x4*)(x + i);
    f32x4 f1 = *(const f32x4*)(x + i + 4);
    short8 t;
    #pragma unroll
    for (int j = 0; j < 4; j++){ t[j] = (short)f2bf(f0[j]); t[4+j] = (short)f2bf(f1[j]); }
    *(short8*)(xb + i) = t;
  }
}

// ---- MFMA: wave computes all 32 rows x 32 cols (cols [w*32,w*32+32)) ----
__device__ __forceinline__ void mfma_tile(f32x4 acc[2][2],
                                          const unsigned short* agg,
                                          const unsigned short* __restrict__ Wd,
                                          int w, int q, int r){
  #pragma unroll
  for (int kk = 0; kk < 4; kk++){
    const unsigned short* wp = Wd + (size_t)(w*32 + r)*128 + kk*32 + q*8;
    short8 b0 = *(const short8*)wp;
    short8 b1 = *(const short8*)(wp + 16*128);
    #pragma unroll
    for (int mt = 0; mt < 2; mt++){
      short8 av = *(const short8*)&agg[(mt*16 + r)*APITCH + kk*32 + q*8];
      acc[mt][0] = __builtin_amdgcn_mfma_f32_16x16x32_bf16(av, b0, acc[mt][0], 0, 0, 0);
      acc[mt][1] = __builtin_amdgcn_mfma_f32_16x16x32_bf16(av, b1, acc[mt][1], 0, 0, 0);
    }
  }
}

// ---- fused layer (r11 measured-best core). AGG0: layer1 exports its dir-0
// aggregate (bit-identical to the shortcut's gather) to agg0w; layer2 reads it
// sequentially instead of re-gathering 65K random rows.
template<int IS_L2, int AGG0>
__global__ __launch_bounds__(256, 8) void layer_k(
    const unsigned short* __restrict__ H,     // layer input activations [N][128] bf16
    const unsigned short* __restrict__ X,     // xb (shortcut input, L2 only)
    const unsigned short* __restrict__ Wf,    // [1152][128] folded dir weights
    const unsigned short* __restrict__ W3f,   // [128][128] folded shortcut weights (L2)
    const int* __restrict__ cntg, const int* __restrict__ sorted,
    const int* __restrict__ ocnt, const int* __restrict__ overflow,
    const float* __restrict__ biasA, const float* __restrict__ bias3,
    const float* __restrict__ s3v,
    const unsigned short* __restrict__ agg0r, unsigned short* __restrict__ agg0w,
    unsigned short* __restrict__ outB, float* __restrict__ outF){
  __shared__ __align__(16) unsigned short agg[TILE_M*APITCH];    // 8704 B
  __shared__ int skey[TILE_M*SLOTS];                             // 3072 B staged keys
  __shared__ unsigned short skey2[TILE_M*SLOTS];                 // 1536 B sorted src
  __shared__ int cnts[TILE_M];                                   // per-node counts
  __shared__ int po[TILE_M*9];                                   // local bin starts
  __shared__ int wo[TILE_M*9];                                   // counts -> cursors -> ends
  __shared__ int ocs;
  const int tid = threadIdx.x;
  const int w = tid >> 6, lane = tid & 63;
  const int q = lane >> 4, r = lane & 15;
  const int rid = tid >> 4, c = tid & 15;                        // 16 lanes/row, chunk c
  const int m0 = blockIdx.x * TILE_M;

  if (tid < TILE_M){ int v = cntg[m0 + tid]; cnts[tid] = v < SLOTS ? v : SLOTS; }
  if (tid == 255){ int v = *ocnt; ocs = v < OCAP ? v : OCAP; }
  for (int i = tid; i < TILE_M*9; i += 256) wo[i] = 0;
  __syncthreads();

  // stage fixed-slot keys + count per (node,dir): 8 threads per node
  {
    const int nl8 = tid >> 3, sub = tid & 7;
    int e8 = cnts[nl8];
    for (int j = sub; j < e8; j += 8){
      int k = sorted[(m0 + nl8)*SLOTS + j];
      skey[nl8*SLOTS + j] = k;
      atomicAdd(&wo[nl8*9 + (k >> 16)], 1);
    }
  }
  __syncthreads();
  // per-node prefix: po = bin start, wo = scatter cursor (becomes end after scatter)
  if (tid < TILE_M){
    int base = tid*SLOTS;
    #pragma unroll
    for (int d = 0; d < 9; d++){
      int b = tid*9 + d;
      po[b] = base;
      int cc = wo[b];
      wo[b] = base;
      base += cc;
    }
  }
  __syncthreads();
  // scatter staged keys into per-(node,dir) bins (16-bit src)
  {
    const int nl8 = tid >> 3, sub = tid & 7;
    int e8 = cnts[nl8];
    for (int j = sub; j < e8; j += 8){
      int k = skey[nl8*SLOTS + j];
      int pos = atomicAdd(&wo[nl8*9 + (k >> 16)], 1);
      skey2[pos] = (unsigned short)k;
    }
  }
  __syncthreads();

  f32x4 acc[2][2];
  #pragma unroll
  for (int mt = 0; mt < 2; mt++){ acc[mt][0] = (f32x4){0,0,0,0}; acc[mt][1] = (f32x4){0,0,0,0}; }

  #pragma unroll 1
  for (int d = 0; d < 9; d++){
    if (d) __syncthreads();              // agg consumed by previous mfma
    // stream A: row rid
    {
      int b = rid*9 + d;
      int s = po[b], e = wo[b];
      f32x4 a0 = {0,0,0,0}, a1 = {0,0,0,0};
      for (int i = s; i < e; i++){
        int key = skey2[i];
        short8 v = *(const short8*)(H + (size_t)key*128 + c*8);
        acc8(a0, a1, v);
      }
      for (int i = 0; i < ocs; i++){     // overflow (empty in practice)
        if (overflow[i*2] == m0 + rid && (overflow[i*2+1] >> 16) == d){
          short8 v = *(const short8*)(H + (size_t)(overflow[i*2+1] & 0xFFFF)*128 + c*8);
          acc8(a0, a1, v);
        }
      }
      short8 o;
      o[0]=(short)f2bf(a0[0]); o[1]=(short)f2bf(a0[1]); o[2]=(short)f2bf(a0[2]); o[3]=(short)f2bf(a0[3]);
      o[4]=(short)f2bf(a1[0]); o[5]=(short)f2bf(a1[1]); o[6]=(short)f2bf(a1[2]); o[7]=(short)f2bf(a1[3]);
      *(short8*)&agg[rid*APITCH + c*8] = o;
      if (AGG0 && !IS_L2 && d == 0)
        *(short8*)(agg0w + (size_t)(m0 + rid)*128 + c*8) = o;
    }
    // stream B: row rid+16
    {
      int b = (16 + rid)*9 + d;
      int s = po[b], e = wo[b];
      f32x4 a0 = {0,0,0,0}, a1 = {0,0,0,0};
      for (int i = s; i < e; i++){
        int key = skey2[i];
        short8 v = *(const short8*)(H + (size_t)key*128 + c*8);
        acc8(a0, a1, v);
      }
      for (int i = 0; i < ocs; i++){
        if (overflow[i*2] == m0 + 16 + rid && (overflow[i*2+1] >> 16) == d){
          short8 v = *(const short8*)(H + (size_t)(overflow[i*2+1] & 0xFFFF)*128 + c*8);
          acc8(a0, a1, v);
        }
      }
      short8 o;
      o[0]=(short)f2bf(a0[0]); o[1]=(short)f2bf(a0[1]); o[2]=(short)f2bf(a0[2]); o[3]=(short)f2bf(a0[3]);
      o[4]=(short)f2bf(a1[0]); o[5]=(short)f2bf(a1[1]); o[6]=(short)f2bf(a1[2]); o[7]=(short)f2bf(a1[3]);
      *(short8*)&agg[(16 + rid)*APITCH + c*8] = o;
      if (AGG0 && !IS_L2 && d == 0)
        *(short8*)(agg0w + (size_t)(m0 + 16 + rid)*128 + c*8) = o;
    }
    __syncthreads();
    mfma_tile(acc, agg, Wf + (size_t)d*128*128, w, q, r);
  }

  if constexpr (!IS_L2){
    #pragma unroll
    for (int mt = 0; mt < 2; mt++)
      #pragma unroll
      for (int n2 = 0; n2 < 2; n2++){
        int col = w*32 + n2*16 + r;
        float bA = biasA[col];
        #pragma unroll
        for (int rr = 0; rr < 4; rr++){
          int row = m0 + mt*16 + q*4 + rr;
          outB[(size_t)row*128 + col] = f2bf(elu1(acc[mt][n2][rr] + bA));
        }
      }
  } else {
    // 10th phase: shortcut aggregate -- from agg0 (sequential) or re-gather from X
    __syncthreads();                     // agg consumed by last mfma
    if constexpr (AGG0){
      short8 vA = *(const short8*)(agg0r + (size_t)(m0 + rid)*128 + c*8);
      *(short8*)&agg[rid*APITCH + c*8] = vA;
      short8 vB = *(const short8*)(agg0r + (size_t)(m0 + 16 + rid)*128 + c*8);
      *(short8*)&agg[(16 + rid)*APITCH + c*8] = vB;
    } else {
      #pragma unroll
      for (int t2 = 0; t2 < 2; t2++){
        int nl = t2*16 + rid;
        int b = nl*9;
        int s = po[b], e = wo[b];
        f32x4 a0 = {0,0,0,0}, a1 = {0,0,0,0};
        for (int i = s; i < e; i++){
          int key = skey2[i];
          short8 v = *(const short8*)(X + (size_t)key*128 + c*8);
          acc8(a0, a1, v);
        }
        for (int i = 0; i < ocs; i++){
          if (overflow[i*2] == m0 + nl && (overflow[i*2+1] >> 16) == 0){
            short8 v = *(const short8*)(X + (size_t)(overflow[i*2+1] & 0xFFFF)*128 + c*8);
            acc8(a0, a1, v);
          }
        }
        short8 o;
        o[0]=(short)f2bf(a0[0]); o[1]=(short)f2bf(a0[1]); o[2]=(short)f2bf(a0[2]); o[3]=(short)f2bf(a0[3]);
        o[4]=(short)f2bf(a1[0]); o[5]=(short)f2bf(a1[1]); o[6]=(short)f2bf(a1[2]); o[7]=(short)f2bf(a1[3]);
        *(short8*)&agg[nl*APITCH + c*8] = o;
      }
    }
    __syncthreads();
    f32x4 sca[2][2];
    #pragma unroll
    for (int mt = 0; mt < 2; mt++){ sca[mt][0] = (f32x4){0,0,0,0}; sca[mt][1] = (f32x4){0,0,0,0}; }
    mfma_tile(sca, agg, W3f, w, q, r);
    #pragma unroll
    for (int mt = 0; mt < 2; mt++)
      #pragma unroll
      for (int n2 = 0; n2 < 2; n2++){
        int col = w*32 + n2*16 + r;
        float bA = biasA[col], b3 = bias3[col], s3 = s3v[col];
        #pragma unroll
        for (int rr = 0; rr < 4; rr++){
          int row = m0 + mt*16 + q*4 + rr;
          float h = elu1(acc[mt][n2][rr] + bA);
          outF[(size_t)row*128 + col] = elu1(h*s3 + sca[mt][n2][rr] + b3);
        }
      }
  }
}

extern "C" void kernel_launch(void* const* d_in, const int* in_sizes, int n_in,
                              void* d_out, int out_size, void* d_ws, size_t ws_size,
                              hipStream_t stream){
  const float* x   = (const float*)d_in[0];
  const int*   ei  = (const int*)d_in[1];
  const int*   sel = (const int*)d_in[2];
  const float* W1  = (const float*)d_in[3];
  const float* b1  = (const float*)d_in[4];
  const float* g1  = (const float*)d_in[5];
  const float* be1 = (const float*)d_in[6];
  const float* rm1 = (const float*)d_in[7];
  const float* rv1 = (const float*)d_in[8];
  const float* W2  = (const float*)d_in[9];
  const float* b2  = (const float*)d_in[10];
  const float* g2  = (const float*)d_in[11];
  const float* be2 = (const float*)d_in[12];
  const float* rm2 = (const float*)d_in[13];
  const float* rv2 = (const float*)d_in[14];
  const float* W3  = (const float*)d_in[15];
  const float* b3  = (const float*)d_in[16];
  const float* g3  = (const float*)d_in[17];
  const float* be3 = (const float*)d_in[18];
  const float* rm3 = (const float*)d_in[19];
  const float* rv3 = (const float*)d_in[20];

  char* ws = (char*)d_ws;
  unsigned short* xb   = (unsigned short*)(ws);                  // 16,777,216 B
  unsigned short* h1   = (unsigned short*)(ws + 16777216);       // 16,777,216 B
  unsigned short* Wt1  = (unsigned short*)(ws + 33554432);       // 327,680 B
  unsigned short* Wt2  = (unsigned short*)(ws + 33882112);       // 294,912 B
  float* bias1  = (float*)(ws + 34177024);
  float* bias2  = bias1 + 128;
  float* bias3  = bias1 + 256;
  float* s3v    = bias1 + 384;
  int* cnt      = (int*)(ws + 34179072);                         // 262,144 B
  int* ocnt     = (int*)(ws + 34441216);                         // 256 B
  int* overflow = (int*)(ws + 34441472);                         // 524,288 B
  int* sorted   = (int*)(ws + 34965760);                         // 6,291,456 B -> ends 41,257,216
  unsigned short* agg0 = (unsigned short*)(ws + 41257216);       // 16,777,216 B (optional)
  const size_t NEED_AGG0 = 41257216ull + 16777216ull;            // 58,034,432

  const int* srcp = ei;
  const int* dstp = ei + NEDGE;
  const bool use_agg0 = ws_size >= NEED_AGG0;

  hipMemsetAsync(cnt, 0, 262400, stream);                        // cnt + ocnt
  fuse_k<<<7617, 256, 0, stream>>>(x, xb, W1, W2, W3,
                                   b1, g1, be1, rm1, rv1,
                                   b2, g2, be2, rm2, rv2,
                                   b3, g3, be3, rm3, rv3,
                                   Wt1, Wt2, bias1, bias2, bias3, s3v,
                                   cnt, ocnt, overflow,
                                   srcp, dstp, sel, sorted);

  if (use_agg0){
    layer_k<0,1><<<2048, 256, 0, stream>>>(xb, nullptr, Wt1, nullptr, cnt, sorted,
                                           ocnt, overflow,
                                           bias1, nullptr, nullptr,
                                           nullptr, agg0, h1, nullptr);
    layer_k<1,1><<<2048, 256, 0, stream>>>(h1, xb, Wt2, Wt1 + 1152*128, cnt, sorted,
                                           ocnt, overflow,
                                           bias2, bias3, s3v,
                                           agg0, nullptr, nullptr, (float*)d_out);
  } else {
    layer_k<0,0><<<2048, 256, 0, stream>>>(xb, nullptr, Wt1, nullptr, cnt, sorted,
                                           ocnt, overflow,
                                           bias1, nullptr, nullptr,
                                           nullptr, nullptr, h1, nullptr);
    layer_k<1,0><<<2048, 256, 0, stream>>>(h1, xb, Wt2, Wt1 + 1152*128, cnt, sorted,
                                           ocnt, overflow,
                                           bias2, bias3, s3v,
                                           nullptr, nullptr, nullptr, (float*)d_out);
  }
}